// Round 8
// baseline (226.501 us; speedup 1.0000x reference)
//
#include <hip/hip_runtime.h>
#include <hip/hip_bf16.h>

// Problem constants
#define BATCH 2
#define SQn 2048
#define SKn 2048
#define DMODEL 1024
#define NH 16
#define HD 64
#define NPOS 257          // 2*128+1
#define RWIN 128          // rel_pos_max_distance
#define RADIUS 256        // local attention radius

typedef __attribute__((ext_vector_type(8))) short bf16x8;
typedef __attribute__((ext_vector_type(4))) float f32x4;

static __device__ __forceinline__ unsigned short f2bf(float f) {
    union { float f; unsigned u; } v; v.f = f;
    unsigned r = (v.u + 0x7FFFu + ((v.u >> 16) & 1u)) >> 16;   // RNE
    return (unsigned short)r;
}
static __device__ __forceinline__ float bf2f(unsigned short b) {
    union { unsigned u; float f; } v; v.u = ((unsigned)b) << 16;
    return v.f;
}

static __device__ __forceinline__ void gl_lds16(const unsigned short* g, unsigned short* l) {
    __builtin_amdgcn_global_load_lds(
        (const __attribute__((address_space(1))) unsigned*)g,
        (__attribute__((address_space(3))) unsigned*)l, 16, 0, 0);
}

// swizzle: distinct chunk slot for rows {i, i+4, i+8, i+12} AND {i, i+2}
// -> ds_read_b128 frag reads are 2-way max (free per m136)
#define SWZ(row) (((row) ^ ((row) >> 2)) & 3)

// ---------------------------------------------------------------------------
// Fused fp32 -> bf16 conversion for Q,K,V (3 x 4M floats) and Wq,Wk,Wv,Wo
// (4 x 1M floats). One float4 per thread.
// ---------------------------------------------------------------------------
__global__ __launch_bounds__(256) void convert_kernel(
    const float* __restrict__ Q, const float* __restrict__ K, const float* __restrict__ V,
    const float* __restrict__ Wq, const float* __restrict__ Wk, const float* __restrict__ Wv,
    const float* __restrict__ Wo,
    unsigned short* __restrict__ xb,    // [3][4194304]
    unsigned short* __restrict__ wb,    // [3][1048576]
    unsigned short* __restrict__ wob)   // [1048576]
{
    int i = blockIdx.x * 256 + threadIdx.x;     // float4 index, < 4194304
    const float* src;
    unsigned short* dst;
    int off;
    if (i < 3145728) {
        int which = i >> 20;
        off = i & 1048575;
        src = which == 0 ? Q : (which == 1 ? K : V);
        dst = xb + (size_t)which * 4194304;
    } else {
        int i2 = i - 3145728;
        int which = i2 >> 18;
        off = i2 & 262143;
        src = which == 0 ? Wq : (which == 1 ? Wk : (which == 2 ? Wv : Wo));
        dst = which < 3 ? wb + (size_t)which * 1048576 : wob;
    }
    float4 v4 = ((const float4*)src)[off];
    ushort4 o4;
    o4.x = f2bf(v4.x); o4.y = f2bf(v4.y); o4.z = f2bf(v4.z); o4.w = f2bf(v4.w);
    ((ushort4*)dst)[off] = o4;
}

// ---------------------------------------------------------------------------
// QKV bf16 MFMA GEMM: Y = X(4096x1024) @ W(1024x1024)^T, z slab in {0,1,2}.
// 128x128 tile, BK=32, 256 threads (4 waves 2x2 of 64x64).
// z<2 : bf16 head-split [bh][s][hd].  z==2: bf16 [bh][hd][s] via LDS transpose.
// ---------------------------------------------------------------------------
__global__ __launch_bounds__(256) void mfma_gemm(
    const unsigned short* __restrict__ Xall,
    const unsigned short* __restrict__ Wall,
    unsigned short* __restrict__ Yall)
{
    __shared__ unsigned short sA[128 * 32];
    __shared__ unsigned short sB[128 * 32];
    __shared__ unsigned short sT[64 * 136];   // epilogue transpose scratch (z==2)

    const int tid  = threadIdx.x;
    const int wv   = tid >> 6;
    const int lane = tid & 63;
    const int quad = lane >> 4;
    const int l15  = lane & 15;
    const int z    = blockIdx.z;
    const int m0   = blockIdx.x * 128;
    const int n0   = blockIdx.y * 128;
    const int wr   = (wv >> 1) * 64;
    const int wc   = (wv & 1) * 64;

    const unsigned short* X = Xall + (size_t)z * (4096 * 1024);
    const unsigned short* W = Wall + (size_t)z * (1024 * 1024);

    int aoff[4], boff[4];
#pragma unroll
    for (int t = 0; t < 4; ++t) {
        int row = wr + t * 16 + l15;
        aoff[t] = row * 32 + ((quad ^ SWZ(row)) * 8);
        int col = wc + t * 16 + l15;
        boff[t] = col * 32 + ((quad ^ SWZ(col)) * 8);
    }

    int srow[2], scg[2], sf[2];
#pragma unroll
    for (int r = 0; r < 2; ++r) {
        int f = r * 256 + tid;
        sf[r] = f;
        srow[r] = f >> 2;
        scg[r] = (f & 3) ^ SWZ(srow[r]);
    }

    f32x4 acc[4][4];
#pragma unroll
    for (int i = 0; i < 4; ++i)
#pragma unroll
        for (int j = 0; j < 4; ++j)
            acc[i][j] = (f32x4){0.f, 0.f, 0.f, 0.f};

    for (int k0 = 0; k0 < 1024; k0 += 32) {
        __syncthreads();
#pragma unroll
        for (int r = 0; r < 2; ++r) {
            gl_lds16(X + (size_t)(m0 + srow[r]) * 1024 + k0 + scg[r] * 8, &sA[sf[r] * 8]);
            gl_lds16(W + (size_t)(n0 + srow[r]) * 1024 + k0 + scg[r] * 8, &sB[sf[r] * 8]);
        }
        __syncthreads();

        bf16x8 af[4], bfr[4];
#pragma unroll
        for (int t = 0; t < 4; ++t) af[t]  = *(const bf16x8*)&sA[aoff[t]];
#pragma unroll
        for (int t = 0; t < 4; ++t) bfr[t] = *(const bf16x8*)&sB[boff[t]];
#pragma unroll
        for (int i = 0; i < 4; ++i)
#pragma unroll
            for (int j = 0; j < 4; ++j)
                acc[i][j] = __builtin_amdgcn_mfma_f32_16x16x32_bf16(af[i], bfr[j], acc[i][j], 0, 0, 0);
    }

    unsigned short* Y = Yall + (size_t)z * (4096 * 1024);
    const int b_ = m0 >> 11;            // batch (tile never straddles)
    const int s0 = m0 & (SQn - 1);

    if (z < 2) {
        // head-split [bh][s][hd]
#pragma unroll
        for (int i = 0; i < 4; ++i) {
            int mbase = s0 + wr + i * 16 + quad * 4;
#pragma unroll
            for (int j = 0; j < 4; ++j) {
                int col = n0 + wc + j * 16 + l15;
                int h = col >> 6, dd = col & 63;
                unsigned short* yb = Y + (((size_t)(b_ * NH + h) * SQn) << 6) + dd;
#pragma unroll
                for (int r = 0; r < 4; ++r)
                    yb[(size_t)(mbase + r) << 6] = f2bf(acc[i][j][r]);
            }
        }
    } else {
        // V: [bh][hd][s] via LDS transpose, coalesced dwordx4 stores.
        // Per head slab: sT[dd(64)][m(128)], stride 136 -> 1024 uint4, 4 iters.
#pragma unroll
        for (int hh = 0; hh < 2; ++hh) {
            __syncthreads();
            if ((wv & 1) == hh) {
#pragma unroll
                for (int i = 0; i < 4; ++i) {
                    int mloc = wr + i * 16 + quad * 4;
#pragma unroll
                    for (int j = 0; j < 4; ++j) {
                        ushort4 pk;
                        pk.x = f2bf(acc[i][j][0]);
                        pk.y = f2bf(acc[i][j][1]);
                        pk.z = f2bf(acc[i][j][2]);
                        pk.w = f2bf(acc[i][j][3]);
                        *(ushort4*)&sT[(j * 16 + l15) * 136 + mloc] = pk;
                    }
                }
            }
            __syncthreads();
            int h = (n0 >> 6) + hh;
            unsigned short* yb = Y + ((size_t)(b_ * NH + h) * HD) * SKn + s0;
#pragma unroll
            for (int it = 0; it < 4; ++it) {
                int u = it * 256 + tid;
                int dd = u >> 4, mc = u & 15;
                uint4 val = *(const uint4*)&sT[dd * 136 + mc * 8];
                *(uint4*)(yb + (size_t)dd * SKn + mc * 8) = val;
            }
        }
    }
}

// ---------------------------------------------------------------------------
// Output-projection GEMM: out(4096x1024 fp32) = aob(4096x1024 bf16) @ Wo^T.
// 64x128 tile -> 512 blocks (2/CU). 4 waves 2x2 over (32,64); acc[2][4].
// ---------------------------------------------------------------------------
__global__ __launch_bounds__(256) void gemm_out(
    const unsigned short* __restrict__ X,
    const unsigned short* __restrict__ W,
    float* __restrict__ Y)
{
    __shared__ unsigned short sA[64 * 32];
    __shared__ unsigned short sB[128 * 32];

    const int tid  = threadIdx.x;
    const int wv   = tid >> 6;
    const int lane = tid & 63;
    const int quad = lane >> 4;
    const int l15  = lane & 15;
    const int m0   = blockIdx.x * 64;
    const int n0   = blockIdx.y * 128;
    const int wr   = (wv >> 1) * 32;
    const int wc   = (wv & 1) * 64;

    int aoff[2], boff[4];
#pragma unroll
    for (int i = 0; i < 2; ++i) {
        int row = wr + i * 16 + l15;
        aoff[i] = row * 32 + ((quad ^ SWZ(row)) * 8);
    }
#pragma unroll
    for (int j = 0; j < 4; ++j) {
        int col = wc + j * 16 + l15;
        boff[j] = col * 32 + ((quad ^ SWZ(col)) * 8);
    }

    const int af_  = tid;
    const int arow = af_ >> 2;
    const int acs  = (af_ & 3) ^ SWZ(arow);
    int bf_[2], brow[2], bcs[2];
#pragma unroll
    for (int r = 0; r < 2; ++r) {
        int f = r * 256 + tid;
        bf_[r] = f; brow[r] = f >> 2; bcs[r] = (f & 3) ^ SWZ(brow[r]);
    }

    f32x4 acc[2][4];
#pragma unroll
    for (int i = 0; i < 2; ++i)
#pragma unroll
        for (int j = 0; j < 4; ++j)
            acc[i][j] = (f32x4){0.f, 0.f, 0.f, 0.f};

    for (int k0 = 0; k0 < 1024; k0 += 32) {
        __syncthreads();
        gl_lds16(X + (size_t)(m0 + arow) * 1024 + k0 + acs * 8, &sA[af_ * 8]);
#pragma unroll
        for (int r = 0; r < 2; ++r)
            gl_lds16(W + (size_t)(n0 + brow[r]) * 1024 + k0 + bcs[r] * 8, &sB[bf_[r] * 8]);
        __syncthreads();

        bf16x8 af[2], bfr[4];
#pragma unroll
        for (int i = 0; i < 2; ++i) af[i]  = *(const bf16x8*)&sA[aoff[i]];
#pragma unroll
        for (int j = 0; j < 4; ++j) bfr[j] = *(const bf16x8*)&sB[boff[j]];
#pragma unroll
        for (int i = 0; i < 2; ++i)
#pragma unroll
            for (int j = 0; j < 4; ++j)
                acc[i][j] = __builtin_amdgcn_mfma_f32_16x16x32_bf16(af[i], bfr[j], acc[i][j], 0, 0, 0);
    }

#pragma unroll
    for (int i = 0; i < 2; ++i) {
        int mbase = m0 + wr + i * 16 + quad * 4;
#pragma unroll
        for (int j = 0; j < 4; ++j) {
            int col = n0 + wc + j * 16 + l15;
#pragma unroll
            for (int r = 0; r < 4; ++r)
                Y[(size_t)(mbase + r) * DMODEL + col] = acc[i][j][r];
        }
    }
}

// ---------------------------------------------------------------------------
// E (P x D) fp32 -> relTb[h][p][d] bf16, rel[h][p][d] = E[p, d*NH + h]
// ---------------------------------------------------------------------------
__global__ __launch_bounds__(256) void relt_kernel(
    const float* __restrict__ E, unsigned short* __restrict__ relTb)
{
    int idx = blockIdx.x * 256 + threadIdx.x;
    const int total = NH * NPOS * HD;
    if (idx < total) {
        int d = idx & (HD - 1);
        int p = (idx >> 6) % NPOS;
        int h = idx / (NPOS * HD);
        relTb[idx] = f2bf(E[(size_t)p * DMODEL + d * NH + h]);
    }
}

// ---------------------------------------------------------------------------
// MFMA flash-style local attention, v3.
// XCD-aware swizzle: blockIdx%8 ~ XCD; each XCD gets 4 heads x 32 qtiles
// (K+V+Q+rel per XCD ~3.2MB < 4MB L2). Single-buffer software pipeline:
// frag ds_reads -> barrier -> issue next tile's global_load_lds -> compute
// (staging latency hidden behind softmax VALU + 16 MFMA per tile).
// ---------------------------------------------------------------------------
#define BIAS_S 9.765625e-4f   // 1/1024

__global__ __launch_bounds__(256) void attn_mfma(
    const unsigned short* __restrict__ q,
    const unsigned short* __restrict__ k,
    const unsigned short* __restrict__ vT,
    const unsigned short* __restrict__ relTb,
    unsigned short* __restrict__ aob)
{
    __shared__ unsigned short sQ[64 * 64];     // swizzled, unpadded
    __shared__ unsigned short sK[64 * 64];
    __shared__ unsigned short sVt[64 * 64];
    __shared__ unsigned short sP[4][16 * 72];  // per-wave, padded stride 72
    __shared__ signed char    sq8[64 * 260];   // int8 bias, stride 260

    const int tid  = threadIdx.x;
    const int w    = tid >> 6;
    const int lane = tid & 63;
    const int quad = lane >> 4;
    const int l15  = lane & 15;
    // XCD-aware block swizzle (blockIdx%8 ~ XCD round-robin heuristic)
    const int xcd  = blockIdx.x & 7;
    const int sidx = blockIdx.x >> 3;
    const int bh   = (xcd << 2) | (sidx >> 5);
    const int q0   = (sidx & 31) << 6;
    const int h    = bh & (NH - 1);
    const int b    = bh >> 4;

    // hoisted staging descriptors (two 16B issues per thread)
    const int f1 = tid,       row1 = f1 >> 3;
    const int c1 = ((f1 & 7) ^ (row1 & 7)) * 8;
    const int f2 = 256 + tid, row2 = f2 >> 3;
    const int c2 = ((f2 & 7) ^ (row2 & 7)) * 8;

    // ---- stage Q tile ----
    {
        const unsigned short* gq = q + ((size_t)bh * SQn + q0) * HD;
        gl_lds16(gq + row1 * HD + c1, &sQ[f1 * 8]);
        gl_lds16(gq + row2 * HD + c2, &sQ[f2 * 8]);
    }
    __syncthreads();

    const int qrow = w * 16 + l15;
    const int qs = (quad ^ (qrow & 7)) * 8;
    bf16x8 a0 = *(const bf16x8*)&sQ[qrow * 64 + qs];
    bf16x8 a1 = *(const bf16x8*)&sQ[qrow * 64 + (qs ^ 32)];

    // ---- qrel phase: int8-encode qrel*0.125 in 1/1024 units ----
    const int myrow = w * 16 + quad * 4;
    for (int c5 = 0; c5 < 5; ++c5) {
        __syncthreads();
        const unsigned short* gr = relTb + ((size_t)h * NPOS + c5 * 64) * HD;
        gl_lds16(gr + row1 * HD + c1, &sK[f1 * 8]);
        gl_lds16(gr + row2 * HD + c2, &sK[f2 * 8]);
        __syncthreads();
#pragma unroll
        for (int t = 0; t < 4; ++t) {
            int prow = t * 16 + l15;
            int ks = (quad ^ (prow & 7)) * 8;
            bf16x8 b0 = *(const bf16x8*)&sK[prow * 64 + ks];
            bf16x8 b1 = *(const bf16x8*)&sK[prow * 64 + (ks ^ 32)];
            f32x4 cc = {0.f, 0.f, 0.f, 0.f};
            cc = __builtin_amdgcn_mfma_f32_16x16x32_bf16(a0, b0, cc, 0, 0, 0);
            cc = __builtin_amdgcn_mfma_f32_16x16x32_bf16(a1, b1, cc, 0, 0, 0);
            int pos = c5 * 64 + t * 16 + l15;
            if (pos < NPOS) {
#pragma unroll
                for (int r = 0; r < 4; ++r) {
                    int iq = (int)rintf(cc[r] * 128.0f);
                    iq = iq < -127 ? -127 : (iq > 127 ? 127 : iq);
                    sq8[(myrow + r) * 260 + pos] = (signed char)iq;
                }
            }
        }
    }
    __syncthreads();

    float bias0[4], bias256[4];
#pragma unroll
    for (int r = 0; r < 4; ++r) {
        bias0[r]   = (float)sq8[(myrow + r) * 260 + 0]   * BIAS_S;
        bias256[r] = (float)sq8[(myrow + r) * 260 + 256] * BIAS_S;
    }

    // ---- main loop (software-pipelined, single buffer) ----
    const int lo = (q0 - RADIUS) > 0 ? (q0 - RADIUS) : 0;
    const int hi = (q0 + 63 + RADIUS) < (SKn - 1) ? (q0 + 63 + RADIUS) : (SKn - 1);
    const int nt = ((hi - lo) >> 6) + 1;
    const int e_ = l15 - quad * 4;

    const unsigned short* kg = k  + (size_t)bh * SKn * HD;
    const unsigned short* vg = vT + (size_t)bh * HD * SKn;

    float lacc[4] = {0.f, 0.f, 0.f, 0.f};
    f32x4 o[4];
#pragma unroll
    for (int t = 0; t < 4; ++t) o[t] = (f32x4){0.f, 0.f, 0.f, 0.f};

    // prologue: stage tile 0
    {
        gl_lds16(kg + (size_t)(lo + row1) * HD + c1, &sK[f1 * 8]);
        gl_lds16(kg + (size_t)(lo + row2) * HD + c2, &sK[f2 * 8]);
        gl_lds16(vg + (size_t)row1 * SKn + lo + c1, &sVt[f1 * 8]);
        gl_lds16(vg + (size_t)row2 * SKn + lo + c2, &sVt[f2 * 8]);
    }

    for (int kt = 0; kt < nt; ++kt) {
        const int kb = lo + (kt << 6);
        __syncthreads();      // vmcnt(0) drain: staging for kt complete

        // read ALL frags for this tile into registers
        bf16x8 kf0[4], kf1[4], vf0[4], vf1[4];
#pragma unroll
        for (int t = 0; t < 4; ++t) {
            int prow = t * 16 + l15;
            int ks = (quad ^ (prow & 7)) * 8;
            kf0[t] = *(const bf16x8*)&sK[prow * 64 + ks];
            kf1[t] = *(const bf16x8*)&sK[prow * 64 + (ks ^ 32)];
            vf0[t] = *(const bf16x8*)&sVt[prow * 64 + ks];
            vf1[t] = *(const bf16x8*)&sVt[prow * 64 + (ks ^ 32)];
        }
        __syncthreads();      // all waves done reading sK/sVt -> buffers free

        if (kt + 1 < nt) {    // stage kt+1 while we compute kt
            const int kb2 = kb + 64;
            gl_lds16(kg + (size_t)(kb2 + row1) * HD + c1, &sK[f1 * 8]);
            gl_lds16(kg + (size_t)(kb2 + row2) * HD + c2, &sK[f2 * 8]);
            gl_lds16(vg + (size_t)row1 * SKn + kb2 + c1, &sVt[f1 * 8]);
            gl_lds16(vg + (size_t)row2 * SKn + kb2 + c2, &sVt[f2 * 8]);
        }

        const int dtbase = kb - q0 - w * 16;
#pragma unroll
        for (int t = 0; t < 4; ++t) {
            const int dt = dtbase + t * 16;
            const int spb = (quad * 4) * 72 + t * 16 + l15;
            if (dt <= -272 || dt >= 272) {
#pragma unroll
                for (int r = 0; r < 4; ++r) sP[w][spb + r * 72] = 0;
            } else {
                f32x4 sc = {0.f, 0.f, 0.f, 0.f};
                sc = __builtin_amdgcn_mfma_f32_16x16x32_bf16(a0, kf0[t], sc, 0, 0, 0);
                sc = __builtin_amdgcn_mfma_f32_16x16x32_bf16(a1, kf1[t], sc, 0, 0, 0);

                float pv[4];
                if (dt >= -112 && dt <= 112) {
                    int idx0 = myrow * 260 + dt + 128 + e_;
#pragma unroll
                    for (int r = 0; r < 4; ++r) {
                        float bf = (float)sq8[idx0 + r * 259] * BIAS_S;
                        pv[r] = __expf(fmaf(sc[r], 0.125f, bf));
                    }
                } else if (dt >= -240 && dt <= -144) {   // flat p=0, all in-window
#pragma unroll
                    for (int r = 0; r < 4; ++r)
                        pv[r] = __expf(fmaf(sc[r], 0.125f, bias0[r]));
                } else if (dt >= 144 && dt <= 240) {     // flat p=256, all in-window
#pragma unroll
                    for (int r = 0; r < 4; ++r)
                        pv[r] = __expf(fmaf(sc[r], 0.125f, bias256[r]));
                } else {    // boundary: dt in {-256,-128,128,256} -> mask + clip
#pragma unroll
                    for (int r = 0; r < 4; ++r) {
                        int d = dt + e_ - r;
                        bool in = (unsigned)(d + RADIUS) <= 2u * RADIUS;
                        int p = d < -RWIN ? 0 : (d > RWIN ? 2 * RWIN : d + RWIN);
                        float bf = (float)sq8[(myrow + r) * 260 + p] * BIAS_S;
                        float e = __expf(fmaf(sc[r], 0.125f, bf));
                        pv[r] = in ? e : 0.0f;
                    }
                }
#pragma unroll
                for (int r = 0; r < 4; ++r) {
                    unsigned short pb = f2bf(pv[r]);
                    sP[w][spb + r * 72] = pb;
                    lacc[r] += bf2f(pb);
                }
            }
        }

        // PV (V frags already in registers)
        bf16x8 p0 = *(const bf16x8*)&sP[w][l15 * 72 + quad * 8];
        bf16x8 p1 = *(const bf16x8*)&sP[w][l15 * 72 + 32 + quad * 8];
#pragma unroll
        for (int t = 0; t < 4; ++t) {
            o[t] = __builtin_amdgcn_mfma_f32_16x16x32_bf16(p0, vf0[t], o[t], 0, 0, 0);
            o[t] = __builtin_amdgcn_mfma_f32_16x16x32_bf16(p1, vf1[t], o[t], 0, 0, 0);
        }
    }

    float linv[4];
#pragma unroll
    for (int r = 0; r < 4; ++r) {
        float l = lacc[r];
#pragma unroll
        for (int off = 1; off <= 8; off <<= 1) l += __shfl_xor(l, off);
        linv[r] = 1.0f / l;
    }

#pragma unroll
    for (int t = 0; t < 4; ++t) {
#pragma unroll
        for (int r = 0; r < 4; ++r) {
            int i = q0 + w * 16 + quad * 4 + r;
            int c = (t * 16 + l15) * NH + h;
            aob[((size_t)b * SQn + i) * DMODEL + c] = f2bf(o[t][r] * linv[r]);
        }
    }
}

// ---------------------------------------------------------------------------
extern "C" void kernel_launch(void* const* d_in, const int* in_sizes, int n_in,
                              void* d_out, int out_size, void* d_ws, size_t ws_size,
                              hipStream_t stream) {
    const float* Q  = (const float*)d_in[0];
    const float* K  = (const float*)d_in[1];
    const float* V  = (const float*)d_in[2];
    const float* Wq = (const float*)d_in[3];
    const float* Wk = (const float*)d_in[4];
    const float* Wv = (const float*)d_in[5];
    const float* Wo = (const float*)d_in[6];
    const float* E  = (const float*)d_in[7];
    float* out = (float*)d_out;

    char* p = (char*)d_ws;
    unsigned short* xb    = (unsigned short*)p; p += (size_t)24 << 20;  // [3][4M] bf16
    unsigned short* wb    = (unsigned short*)p; p += (size_t)6  << 20;  // [3][1M] bf16
    unsigned short* wob   = (unsigned short*)p; p += (size_t)2  << 20;  // [1M] bf16
    unsigned short* head  = (unsigned short*)p; p += (size_t)24 << 20;  // q,k,vT bf16
    unsigned short* relTb = (unsigned short*)p; p += (size_t)1  << 20;
    unsigned short* aob   = (unsigned short*)p;                          // 8 MB

    unsigned short* qb  = head;
    unsigned short* kb  = head + 4194304;
    unsigned short* vTb = head + 8388608;

    dim3 bb(256);
    convert_kernel<<<dim3(16384), bb, 0, stream>>>(Q, K, V, Wq, Wk, Wv, Wo, xb, wb, wob);
    relt_kernel<<<dim3(1028), bb, 0, stream>>>(E, relTb);
    mfma_gemm<<<dim3(32, 8, 3), bb, 0, stream>>>(xb, wb, head);
    attn_mfma<<<dim3(BATCH * NH * (SQn / 64)), bb, 0, stream>>>(qb, kb, vTb, relTb, aob);
    gemm_out<<<dim3(64, 8), bb, 0, stream>>>(aob, wob, out);
}

// Round 9
// 212.425 us; speedup vs baseline: 1.0663x; 1.0663x over previous
//
#include <hip/hip_runtime.h>
#include <hip/hip_bf16.h>

// Problem constants
#define BATCH 2
#define SQn 2048
#define SKn 2048
#define DMODEL 1024
#define NH 16
#define HD 64
#define NPOS 257          // 2*128+1
#define RWIN 128          // rel_pos_max_distance
#define RADIUS 256        // local attention radius

typedef __attribute__((ext_vector_type(8))) short bf16x8;
typedef __attribute__((ext_vector_type(4))) float f32x4;

static __device__ __forceinline__ unsigned short f2bf(float f) {
    union { float f; unsigned u; } v; v.f = f;
    unsigned r = (v.u + 0x7FFFu + ((v.u >> 16) & 1u)) >> 16;   // RNE
    return (unsigned short)r;
}
static __device__ __forceinline__ float bf2f(unsigned short b) {
    union { unsigned u; float f; } v; v.u = ((unsigned)b) << 16;
    return v.f;
}

static __device__ __forceinline__ void gl_lds16(const unsigned short* g, unsigned short* l) {
    __builtin_amdgcn_global_load_lds(
        (const __attribute__((address_space(1))) unsigned*)g,
        (__attribute__((address_space(3))) unsigned*)l, 16, 0, 0);
}

// swizzle: distinct chunk slot for rows {i, i+4, i+8, i+12} AND {i, i+2}
// -> ds_read_b128 frag reads are 2-way max (free per m136)
#define SWZ(row) (((row) ^ ((row) >> 2)) & 3)

// ---------------------------------------------------------------------------
// Fused fp32 -> bf16 conversion:
//   Q,K,V (3 x 4M) -> xb;  Wq,Wk,Wv (3 x 1M) -> wb;
//   Wo -> woh[h][n][d] = Wo[n][d*16+h]  (head-sliced repack for gemm_out).
// ---------------------------------------------------------------------------
__global__ __launch_bounds__(256) void convert_kernel(
    const float* __restrict__ Q, const float* __restrict__ K, const float* __restrict__ V,
    const float* __restrict__ Wq, const float* __restrict__ Wk, const float* __restrict__ Wv,
    const float* __restrict__ Wo,
    unsigned short* __restrict__ xb,    // [3][4194304]
    unsigned short* __restrict__ wb,    // [3][1048576]
    unsigned short* __restrict__ woh)   // [16][1024][64]
{
    int i = blockIdx.x * 256 + threadIdx.x;     // float4 index, < 4194304
    if (i < 3145728) {
        int which = i >> 20;
        int off = i & 1048575;
        const float* src = which == 0 ? Q : (which == 1 ? K : V);
        unsigned short* dst = xb + (size_t)which * 4194304;
        float4 v4 = ((const float4*)src)[off];
        ushort4 o4;
        o4.x = f2bf(v4.x); o4.y = f2bf(v4.y); o4.z = f2bf(v4.z); o4.w = f2bf(v4.w);
        ((ushort4*)dst)[off] = o4;
    } else {
        int i2 = i - 3145728;
        int which = i2 >> 18;
        int off = i2 & 262143;
        if (which < 3) {
            const float* src = which == 0 ? Wq : (which == 1 ? Wk : Wv);
            unsigned short* dst = wb + (size_t)which * 1048576;
            float4 v4 = ((const float4*)src)[off];
            ushort4 o4;
            o4.x = f2bf(v4.x); o4.y = f2bf(v4.y); o4.z = f2bf(v4.z); o4.w = f2bf(v4.w);
            ((ushort4*)dst)[off] = o4;
        } else {
            // Wo repack: float4 = Wo[n][c0..c0+3], c=d*16+h (4-aligned c0 ->
            // d fixed, h = (c0&15)+j). Scatter 4 ushorts into woh slabs.
            float4 v4 = ((const float4*)Wo)[off];
            int e0 = off * 4;
            int n  = e0 >> 10;
            int c0 = e0 & 1023;
            int d  = c0 >> 4;
            int h0 = c0 & 15;
            woh[((size_t)(h0 + 0) * 1024 + n) * 64 + d] = f2bf(v4.x);
            woh[((size_t)(h0 + 1) * 1024 + n) * 64 + d] = f2bf(v4.y);
            woh[((size_t)(h0 + 2) * 1024 + n) * 64 + d] = f2bf(v4.z);
            woh[((size_t)(h0 + 3) * 1024 + n) * 64 + d] = f2bf(v4.w);
        }
    }
}

// ---------------------------------------------------------------------------
// QKV bf16 MFMA GEMM: Y = X(4096x1024) @ W(1024x1024)^T, z slab in {0,1,2}.
// 128x128 tile, BK=32, 256 threads (4 waves 2x2 of 64x64).
// z<2 : bf16 head-split [bh][s][hd].  z==2: bf16 [bh][hd][s] via LDS transpose.
// ---------------------------------------------------------------------------
__global__ __launch_bounds__(256) void mfma_gemm(
    const unsigned short* __restrict__ Xall,
    const unsigned short* __restrict__ Wall,
    unsigned short* __restrict__ Yall)
{
    __shared__ unsigned short sA[128 * 32];
    __shared__ unsigned short sB[128 * 32];
    __shared__ unsigned short sT[64 * 136];   // epilogue transpose scratch (z==2)

    const int tid  = threadIdx.x;
    const int wv   = tid >> 6;
    const int lane = tid & 63;
    const int quad = lane >> 4;
    const int l15  = lane & 15;
    const int z    = blockIdx.z;
    const int m0   = blockIdx.x * 128;
    const int n0   = blockIdx.y * 128;
    const int wr   = (wv >> 1) * 64;
    const int wc   = (wv & 1) * 64;

    const unsigned short* X = Xall + (size_t)z * (4096 * 1024);
    const unsigned short* W = Wall + (size_t)z * (1024 * 1024);

    int aoff[4], boff[4];
#pragma unroll
    for (int t = 0; t < 4; ++t) {
        int row = wr + t * 16 + l15;
        aoff[t] = row * 32 + ((quad ^ SWZ(row)) * 8);
        int col = wc + t * 16 + l15;
        boff[t] = col * 32 + ((quad ^ SWZ(col)) * 8);
    }

    int srow[2], scg[2], sf[2];
#pragma unroll
    for (int r = 0; r < 2; ++r) {
        int f = r * 256 + tid;
        sf[r] = f;
        srow[r] = f >> 2;
        scg[r] = (f & 3) ^ SWZ(srow[r]);
    }

    f32x4 acc[4][4];
#pragma unroll
    for (int i = 0; i < 4; ++i)
#pragma unroll
        for (int j = 0; j < 4; ++j)
            acc[i][j] = (f32x4){0.f, 0.f, 0.f, 0.f};

    for (int k0 = 0; k0 < 1024; k0 += 32) {
        __syncthreads();
#pragma unroll
        for (int r = 0; r < 2; ++r) {
            gl_lds16(X + (size_t)(m0 + srow[r]) * 1024 + k0 + scg[r] * 8, &sA[sf[r] * 8]);
            gl_lds16(W + (size_t)(n0 + srow[r]) * 1024 + k0 + scg[r] * 8, &sB[sf[r] * 8]);
        }
        __syncthreads();

        bf16x8 af[4], bfr[4];
#pragma unroll
        for (int t = 0; t < 4; ++t) af[t]  = *(const bf16x8*)&sA[aoff[t]];
#pragma unroll
        for (int t = 0; t < 4; ++t) bfr[t] = *(const bf16x8*)&sB[boff[t]];
#pragma unroll
        for (int i = 0; i < 4; ++i)
#pragma unroll
            for (int j = 0; j < 4; ++j)
                acc[i][j] = __builtin_amdgcn_mfma_f32_16x16x32_bf16(af[i], bfr[j], acc[i][j], 0, 0, 0);
    }

    unsigned short* Y = Yall + (size_t)z * (4096 * 1024);
    const int b_ = m0 >> 11;            // batch (tile never straddles)
    const int s0 = m0 & (SQn - 1);

    if (z < 2) {
        // head-split [bh][s][hd]
#pragma unroll
        for (int i = 0; i < 4; ++i) {
            int mbase = s0 + wr + i * 16 + quad * 4;
#pragma unroll
            for (int j = 0; j < 4; ++j) {
                int col = n0 + wc + j * 16 + l15;
                int h = col >> 6, dd = col & 63;
                unsigned short* yb = Y + (((size_t)(b_ * NH + h) * SQn) << 6) + dd;
#pragma unroll
                for (int r = 0; r < 4; ++r)
                    yb[(size_t)(mbase + r) << 6] = f2bf(acc[i][j][r]);
            }
        }
    } else {
        // V: [bh][hd][s] via LDS transpose, coalesced dwordx4 stores.
#pragma unroll
        for (int hh = 0; hh < 2; ++hh) {
            __syncthreads();
            if ((wv & 1) == hh) {
#pragma unroll
                for (int i = 0; i < 4; ++i) {
                    int mloc = wr + i * 16 + quad * 4;
#pragma unroll
                    for (int j = 0; j < 4; ++j) {
                        ushort4 pk;
                        pk.x = f2bf(acc[i][j][0]);
                        pk.y = f2bf(acc[i][j][1]);
                        pk.z = f2bf(acc[i][j][2]);
                        pk.w = f2bf(acc[i][j][3]);
                        *(ushort4*)&sT[(j * 16 + l15) * 136 + mloc] = pk;
                    }
                }
            }
            __syncthreads();
            int h = (n0 >> 6) + hh;
            unsigned short* yb = Y + ((size_t)(b_ * NH + h) * HD) * SKn + s0;
#pragma unroll
            for (int it = 0; it < 4; ++it) {
                int u = it * 256 + tid;
                int dd = u >> 4, mc = u & 15;
                uint4 val = *(const uint4*)&sT[dd * 136 + mc * 8];
                *(uint4*)(yb + (size_t)dd * SKn + mc * 8) = val;
            }
        }
    }
}

// ---------------------------------------------------------------------------
// Output-projection GEMM v2, head-major K order:
//   out[m][n] = sum_h sum_d aoh[b*16+h][s][d] * woh[h][n][d]
// aoh [bh][s][64] and woh [h][n][64] are both K-major contiguous.
// 64x128 tile -> 512 blocks (2/CU); h-loop(16) x k0 in {0,32}; acc[2][4].
// ---------------------------------------------------------------------------
__global__ __launch_bounds__(256) void gemm_out(
    const unsigned short* __restrict__ aoh,
    const unsigned short* __restrict__ woh,
    float* __restrict__ Y)
{
    __shared__ unsigned short sA[64 * 32];
    __shared__ unsigned short sB[128 * 32];

    const int tid  = threadIdx.x;
    const int wv   = tid >> 6;
    const int lane = tid & 63;
    const int quad = lane >> 4;
    const int l15  = lane & 15;
    const int m0   = blockIdx.x * 64;
    const int n0   = blockIdx.y * 128;
    const int wr   = (wv >> 1) * 32;
    const int wc   = (wv & 1) * 64;
    const int b_   = m0 >> 11;
    const int s0   = m0 & (SQn - 1);

    int aoff[2], boff[4];
#pragma unroll
    for (int i = 0; i < 2; ++i) {
        int row = wr + i * 16 + l15;
        aoff[i] = row * 32 + ((quad ^ SWZ(row)) * 8);
    }
#pragma unroll
    for (int j = 0; j < 4; ++j) {
        int col = wc + j * 16 + l15;
        boff[j] = col * 32 + ((quad ^ SWZ(col)) * 8);
    }

    const int arow = tid >> 2;
    const int acs  = (tid & 3) ^ SWZ(arow);
    int bf_[2], brow[2], bcs[2];
#pragma unroll
    for (int r = 0; r < 2; ++r) {
        int f = r * 256 + tid;
        bf_[r] = f; brow[r] = f >> 2; bcs[r] = (f & 3) ^ SWZ(brow[r]);
    }

    f32x4 acc[2][4];
#pragma unroll
    for (int i = 0; i < 2; ++i)
#pragma unroll
        for (int j = 0; j < 4; ++j)
            acc[i][j] = (f32x4){0.f, 0.f, 0.f, 0.f};

    for (int h = 0; h < NH; ++h) {
        const unsigned short* Ah = aoh + ((size_t)(b_ * NH + h) * SQn + s0) * HD;
        const unsigned short* Bh = woh + ((size_t)h * 1024 + n0) * HD;
#pragma unroll
        for (int k0 = 0; k0 < 64; k0 += 32) {
            __syncthreads();
            gl_lds16(Ah + (size_t)arow * HD + k0 + acs * 8, &sA[tid * 8]);
#pragma unroll
            for (int r = 0; r < 2; ++r)
                gl_lds16(Bh + (size_t)brow[r] * HD + k0 + bcs[r] * 8, &sB[bf_[r] * 8]);
            __syncthreads();

            bf16x8 af[2], bfr[4];
#pragma unroll
            for (int i = 0; i < 2; ++i) af[i]  = *(const bf16x8*)&sA[aoff[i]];
#pragma unroll
            for (int j = 0; j < 4; ++j) bfr[j] = *(const bf16x8*)&sB[boff[j]];
#pragma unroll
            for (int i = 0; i < 2; ++i)
#pragma unroll
                for (int j = 0; j < 4; ++j)
                    acc[i][j] = __builtin_amdgcn_mfma_f32_16x16x32_bf16(af[i], bfr[j], acc[i][j], 0, 0, 0);
        }
    }

#pragma unroll
    for (int i = 0; i < 2; ++i) {
        int mbase = m0 + wr + i * 16 + quad * 4;
#pragma unroll
        for (int j = 0; j < 4; ++j) {
            int col = n0 + wc + j * 16 + l15;
#pragma unroll
            for (int r = 0; r < 4; ++r)
                Y[(size_t)(mbase + r) * DMODEL + col] = acc[i][j][r];
        }
    }
}

// ---------------------------------------------------------------------------
// E (P x D) fp32 -> relTb[h][p][d] bf16, rel[h][p][d] = E[p, d*NH + h]
// ---------------------------------------------------------------------------
__global__ __launch_bounds__(256) void relt_kernel(
    const float* __restrict__ E, unsigned short* __restrict__ relTb)
{
    int idx = blockIdx.x * 256 + threadIdx.x;
    const int total = NH * NPOS * HD;
    if (idx < total) {
        int d = idx & (HD - 1);
        int p = (idx >> 6) % NPOS;
        int h = idx / (NPOS * HD);
        relTb[idx] = f2bf(E[(size_t)p * DMODEL + d * NH + h]);
    }
}

// ---------------------------------------------------------------------------
// MFMA flash-style local attention, v4.
// XCD swizzle (4 heads/XCD, K+V+Q+rel ~3.2MB < 4MB L2) + single-buffer
// software pipeline + per-block-dense output aoh[bh][s][d] (8KB contiguous
// per block -> full write-combining on any XCD).
// ---------------------------------------------------------------------------
#define BIAS_S 9.765625e-4f   // 1/1024

__global__ __launch_bounds__(256) void attn_mfma(
    const unsigned short* __restrict__ q,
    const unsigned short* __restrict__ k,
    const unsigned short* __restrict__ vT,
    const unsigned short* __restrict__ relTb,
    unsigned short* __restrict__ aoh)
{
    __shared__ unsigned short sQ[64 * 64];     // swizzled, unpadded
    __shared__ unsigned short sK[64 * 64];
    __shared__ unsigned short sVt[64 * 64];
    __shared__ unsigned short sP[4][16 * 72];  // per-wave, padded stride 72
    __shared__ signed char    sq8[64 * 260];   // int8 bias, stride 260

    const int tid  = threadIdx.x;
    const int w    = tid >> 6;
    const int lane = tid & 63;
    const int quad = lane >> 4;
    const int l15  = lane & 15;
    // XCD-aware block swizzle (blockIdx%8 ~ XCD round-robin heuristic)
    const int xcd  = blockIdx.x & 7;
    const int sidx = blockIdx.x >> 3;
    const int bh   = (xcd << 2) | (sidx >> 5);
    const int q0   = (sidx & 31) << 6;
    const int h    = bh & (NH - 1);

    // hoisted staging descriptors (two 16B issues per thread)
    const int f1 = tid,       row1 = f1 >> 3;
    const int c1 = ((f1 & 7) ^ (row1 & 7)) * 8;
    const int f2 = 256 + tid, row2 = f2 >> 3;
    const int c2 = ((f2 & 7) ^ (row2 & 7)) * 8;

    // ---- stage Q tile ----
    {
        const unsigned short* gq = q + ((size_t)bh * SQn + q0) * HD;
        gl_lds16(gq + row1 * HD + c1, &sQ[f1 * 8]);
        gl_lds16(gq + row2 * HD + c2, &sQ[f2 * 8]);
    }
    __syncthreads();

    const int qrow = w * 16 + l15;
    const int qs = (quad ^ (qrow & 7)) * 8;
    bf16x8 a0 = *(const bf16x8*)&sQ[qrow * 64 + qs];
    bf16x8 a1 = *(const bf16x8*)&sQ[qrow * 64 + (qs ^ 32)];

    // ---- qrel phase: int8-encode qrel*0.125 in 1/1024 units ----
    const int myrow = w * 16 + quad * 4;
    for (int c5 = 0; c5 < 5; ++c5) {
        __syncthreads();
        const unsigned short* gr = relTb + ((size_t)h * NPOS + c5 * 64) * HD;
        gl_lds16(gr + row1 * HD + c1, &sK[f1 * 8]);
        gl_lds16(gr + row2 * HD + c2, &sK[f2 * 8]);
        __syncthreads();
#pragma unroll
        for (int t = 0; t < 4; ++t) {
            int prow = t * 16 + l15;
            int ks = (quad ^ (prow & 7)) * 8;
            bf16x8 b0 = *(const bf16x8*)&sK[prow * 64 + ks];
            bf16x8 b1 = *(const bf16x8*)&sK[prow * 64 + (ks ^ 32)];
            f32x4 cc = {0.f, 0.f, 0.f, 0.f};
            cc = __builtin_amdgcn_mfma_f32_16x16x32_bf16(a0, b0, cc, 0, 0, 0);
            cc = __builtin_amdgcn_mfma_f32_16x16x32_bf16(a1, b1, cc, 0, 0, 0);
            int pos = c5 * 64 + t * 16 + l15;
            if (pos < NPOS) {
#pragma unroll
                for (int r = 0; r < 4; ++r) {
                    int iq = (int)rintf(cc[r] * 128.0f);
                    iq = iq < -127 ? -127 : (iq > 127 ? 127 : iq);
                    sq8[(myrow + r) * 260 + pos] = (signed char)iq;
                }
            }
        }
    }
    __syncthreads();

    float bias0[4], bias256[4];
#pragma unroll
    for (int r = 0; r < 4; ++r) {
        bias0[r]   = (float)sq8[(myrow + r) * 260 + 0]   * BIAS_S;
        bias256[r] = (float)sq8[(myrow + r) * 260 + 256] * BIAS_S;
    }

    // ---- main loop (software-pipelined, single buffer) ----
    const int lo = (q0 - RADIUS) > 0 ? (q0 - RADIUS) : 0;
    const int hi = (q0 + 63 + RADIUS) < (SKn - 1) ? (q0 + 63 + RADIUS) : (SKn - 1);
    const int nt = ((hi - lo) >> 6) + 1;
    const int e_ = l15 - quad * 4;

    const unsigned short* kg = k  + (size_t)bh * SKn * HD;
    const unsigned short* vg = vT + (size_t)bh * HD * SKn;

    float lacc[4] = {0.f, 0.f, 0.f, 0.f};
    f32x4 o[4];
#pragma unroll
    for (int t = 0; t < 4; ++t) o[t] = (f32x4){0.f, 0.f, 0.f, 0.f};

    // prologue: stage tile 0
    {
        gl_lds16(kg + (size_t)(lo + row1) * HD + c1, &sK[f1 * 8]);
        gl_lds16(kg + (size_t)(lo + row2) * HD + c2, &sK[f2 * 8]);
        gl_lds16(vg + (size_t)row1 * SKn + lo + c1, &sVt[f1 * 8]);
        gl_lds16(vg + (size_t)row2 * SKn + lo + c2, &sVt[f2 * 8]);
    }

    for (int kt = 0; kt < nt; ++kt) {
        const int kb = lo + (kt << 6);
        __syncthreads();      // vmcnt(0) drain: staging for kt complete

        // read ALL frags for this tile into registers
        bf16x8 kf0[4], kf1[4], vf0[4], vf1[4];
#pragma unroll
        for (int t = 0; t < 4; ++t) {
            int prow = t * 16 + l15;
            int ks = (quad ^ (prow & 7)) * 8;
            kf0[t] = *(const bf16x8*)&sK[prow * 64 + ks];
            kf1[t] = *(const bf16x8*)&sK[prow * 64 + (ks ^ 32)];
            vf0[t] = *(const bf16x8*)&sVt[prow * 64 + ks];
            vf1[t] = *(const bf16x8*)&sVt[prow * 64 + (ks ^ 32)];
        }
        __syncthreads();      // all waves done reading sK/sVt -> buffers free

        if (kt + 1 < nt) {    // stage kt+1 while we compute kt
            const int kb2 = kb + 64;
            gl_lds16(kg + (size_t)(kb2 + row1) * HD + c1, &sK[f1 * 8]);
            gl_lds16(kg + (size_t)(kb2 + row2) * HD + c2, &sK[f2 * 8]);
            gl_lds16(vg + (size_t)row1 * SKn + kb2 + c1, &sVt[f1 * 8]);
            gl_lds16(vg + (size_t)row2 * SKn + kb2 + c2, &sVt[f2 * 8]);
        }

        const int dtbase = kb - q0 - w * 16;
#pragma unroll
        for (int t = 0; t < 4; ++t) {
            const int dt = dtbase + t * 16;
            const int spb = (quad * 4) * 72 + t * 16 + l15;
            if (dt <= -272 || dt >= 272) {
#pragma unroll
                for (int r = 0; r < 4; ++r) sP[w][spb + r * 72] = 0;
            } else {
                f32x4 sc = {0.f, 0.f, 0.f, 0.f};
                sc = __builtin_amdgcn_mfma_f32_16x16x32_bf16(a0, kf0[t], sc, 0, 0, 0);
                sc = __builtin_amdgcn_mfma_f32_16x16x32_bf16(a1, kf1[t], sc, 0, 0, 0);

                float pv[4];
                if (dt >= -112 && dt <= 112) {
                    int idx0 = myrow * 260 + dt + 128 + e_;
#pragma unroll
                    for (int r = 0; r < 4; ++r) {
                        float bf = (float)sq8[idx0 + r * 259] * BIAS_S;
                        pv[r] = __expf(fmaf(sc[r], 0.125f, bf));
                    }
                } else if (dt >= -240 && dt <= -144) {   // flat p=0, all in-window
#pragma unroll
                    for (int r = 0; r < 4; ++r)
                        pv[r] = __expf(fmaf(sc[r], 0.125f, bias0[r]));
                } else if (dt >= 144 && dt <= 240) {     // flat p=256, all in-window
#pragma unroll
                    for (int r = 0; r < 4; ++r)
                        pv[r] = __expf(fmaf(sc[r], 0.125f, bias256[r]));
                } else {    // boundary: dt in {-256,-128,128,256} -> mask + clip
#pragma unroll
                    for (int r = 0; r < 4; ++r) {
                        int d = dt + e_ - r;
                        bool in = (unsigned)(d + RADIUS) <= 2u * RADIUS;
                        int p = d < -RWIN ? 0 : (d > RWIN ? 2 * RWIN : d + RWIN);
                        float bf = (float)sq8[(myrow + r) * 260 + p] * BIAS_S;
                        float e = __expf(fmaf(sc[r], 0.125f, bf));
                        pv[r] = in ? e : 0.0f;
                    }
                }
#pragma unroll
                for (int r = 0; r < 4; ++r) {
                    unsigned short pb = f2bf(pv[r]);
                    sP[w][spb + r * 72] = pb;
                    lacc[r] += bf2f(pb);
                }
            }
        }

        // PV (V frags already in registers)
        bf16x8 p0 = *(const bf16x8*)&sP[w][l15 * 72 + quad * 8];
        bf16x8 p1 = *(const bf16x8*)&sP[w][l15 * 72 + 32 + quad * 8];
#pragma unroll
        for (int t = 0; t < 4; ++t) {
            o[t] = __builtin_amdgcn_mfma_f32_16x16x32_bf16(p0, vf0[t], o[t], 0, 0, 0);
            o[t] = __builtin_amdgcn_mfma_f32_16x16x32_bf16(p1, vf1[t], o[t], 0, 0, 0);
        }
    }

    float linv[4];
#pragma unroll
    for (int r = 0; r < 4; ++r) {
        float l = lacc[r];
#pragma unroll
        for (int off = 1; off <= 8; off <<= 1) l += __shfl_xor(l, off);
        linv[r] = 1.0f / l;
    }

    // epilogue: per-block dense aoh[bh][s][d] (8 KB contiguous per block)
    unsigned short* ob = aoh + ((size_t)bh * SQn + q0) * HD;
#pragma unroll
    for (int t = 0; t < 4; ++t) {
#pragma unroll
        for (int r = 0; r < 4; ++r) {
            int irow = w * 16 + quad * 4 + r;
            ob[irow * HD + t * 16 + l15] = f2bf(o[t][r] * linv[r]);
        }
    }
}

// ---------------------------------------------------------------------------
extern "C" void kernel_launch(void* const* d_in, const int* in_sizes, int n_in,
                              void* d_out, int out_size, void* d_ws, size_t ws_size,
                              hipStream_t stream) {
    const float* Q  = (const float*)d_in[0];
    const float* K  = (const float*)d_in[1];
    const float* V  = (const float*)d_in[2];
    const float* Wq = (const float*)d_in[3];
    const float* Wk = (const float*)d_in[4];
    const float* Wv = (const float*)d_in[5];
    const float* Wo = (const float*)d_in[6];
    const float* E  = (const float*)d_in[7];
    float* out = (float*)d_out;

    char* p = (char*)d_ws;
    unsigned short* xb    = (unsigned short*)p; p += (size_t)24 << 20;  // [3][4M] bf16
    unsigned short* wb    = (unsigned short*)p; p += (size_t)6  << 20;  // [3][1M] bf16
    unsigned short* woh   = (unsigned short*)p; p += (size_t)2  << 20;  // [16][1024][64]
    unsigned short* head  = (unsigned short*)p; p += (size_t)24 << 20;  // q,k,vT bf16
    unsigned short* relTb = (unsigned short*)p; p += (size_t)1  << 20;
    unsigned short* aoh   = (unsigned short*)p;                          // 8 MB

    unsigned short* qb  = head;
    unsigned short* kb  = head + 4194304;
    unsigned short* vTb = head + 8388608;

    dim3 bb(256);
    convert_kernel<<<dim3(16384), bb, 0, stream>>>(Q, K, V, Wq, Wk, Wv, Wo, xb, wb, woh);
    relt_kernel<<<dim3(1028), bb, 0, stream>>>(E, relTb);
    mfma_gemm<<<dim3(32, 8, 3), bb, 0, stream>>>(xb, wb, head);
    attn_mfma<<<dim3(BATCH * NH * (SQn / 64)), bb, 0, stream>>>(qb, kb, vTb, relTb, aoh);
    gemm_out<<<dim3(64, 8), bb, 0, stream>>>(aoh, woh, out);
}